// Round 11
// baseline (322.828 us; speedup 1.0000x reference)
//
#include <hip/hip_runtime.h>
#include <math.h>

constexpr int DIM_   = 512;
constexpr int INNER_ = 1024;
constexpr int NHEAD  = 16;
constexpr int BATCH  = 2;
constexpr int SEQ_   = 2048;
constexpr int TOK    = BATCH * SEQ_;     // 4096
constexpr float EPS_ = 5e-5f;
constexpr float NEPS = 1e-6f;
constexpr float CAPV = 15.0f;

typedef __bf16 bf16_t;
typedef __attribute__((ext_vector_type(8)))  __bf16 bf16x8;
typedef __attribute__((ext_vector_type(4)))  __bf16 bf16x4;
typedef __attribute__((ext_vector_type(16))) float  f32x16;
typedef __attribute__((ext_vector_type(4)))  unsigned int u32x4;

// =============== split-bf16 MFMA GEMM: C[M,N] = A[M,K] @ B[N,K]^T ===============
// MODE: 1 = AhBh, 2 = +AlBh, 3 = +AhBl
template<int BM, int BN, int WM, int WN, int MODE>
__global__ __launch_bounds__(256) void gemm_split(const float* __restrict__ A,
    const float* __restrict__ B, float* __restrict__ C,
    int K, int lda, int ldb, int ldc)
{
    constexpr bool HAS_AL = (MODE >= 2), HAS_BL = (MODE >= 3);
    constexpr int TM = WM / 32, TN = WN / 32, NWC = BN / WN;
    __shared__ __align__(16) bf16_t sAh[BM * 32];
    __shared__ __align__(16) bf16_t sBh[BN * 32];
    __shared__ __align__(16) bf16_t sAl[HAS_AL ? BM * 32 : 8];
    __shared__ __align__(16) bf16_t sBl[HAS_BL ? BN * 32 : 8];
    const int bm = blockIdx.y * BM, bn = blockIdx.x * BN;
    const int tid = threadIdx.x, w = tid >> 6, l = tid & 63;
    const int l31 = l & 31, lh = l >> 5;
    const int wr = w / NWC, wc = w % NWC;
    f32x16 acc[TM][TN];
#pragma unroll
    for (int i = 0; i < TM; ++i)
#pragma unroll
        for (int j = 0; j < TN; ++j)
#pragma unroll
            for (int r = 0; r < 16; ++r) acc[i][j][r] = 0.f;

    for (int k0 = 0; k0 < K; k0 += 32) {
#pragma unroll
        for (int it = 0; it < BM * 4 / 256; ++it) {
            int gi = tid + it * 256; int row = gi >> 2, g = gi & 3;
            const float* src = A + (size_t)(bm + row) * lda + k0 + g * 8;
            float4 u0 = *(const float4*)src, u1 = *(const float4*)(src + 4);
            float va[8] = {u0.x, u0.y, u0.z, u0.w, u1.x, u1.y, u1.z, u1.w};
            bf16x8 h, lo2;
#pragma unroll
            for (int e = 0; e < 8; ++e) {
                bf16_t hv = (bf16_t)va[e]; h[e] = hv;
                if constexpr (HAS_AL) lo2[e] = (bf16_t)(va[e] - (float)hv);
            }
            int off = row * 32 + ((g ^ (row & 3)) << 3);
            *(bf16x8*)&sAh[off] = h;
            if constexpr (HAS_AL) *(bf16x8*)&sAl[off] = lo2;
        }
#pragma unroll
        for (int it = 0; it < BN * 4 / 256; ++it) {
            int gi = tid + it * 256; int row = gi >> 2, g = gi & 3;
            const float* src = B + (size_t)(bn + row) * ldb + k0 + g * 8;
            float4 u0 = *(const float4*)src, u1 = *(const float4*)(src + 4);
            float va[8] = {u0.x, u0.y, u0.z, u0.w, u1.x, u1.y, u1.z, u1.w};
            bf16x8 h, lo2;
#pragma unroll
            for (int e = 0; e < 8; ++e) {
                bf16_t hv = (bf16_t)va[e]; h[e] = hv;
                if constexpr (HAS_BL) lo2[e] = (bf16_t)(va[e] - (float)hv);
            }
            int off = row * 32 + ((g ^ (row & 3)) << 3);
            *(bf16x8*)&sBh[off] = h;
            if constexpr (HAS_BL) *(bf16x8*)&sBl[off] = lo2;
        }
        __syncthreads();
#pragma unroll
        for (int ks = 0; ks < 2; ++ks) {
            const int gk = 2 * ks + lh;
            bf16x8 af[TM], alf[TM], bfv[TN], blf[TN];
#pragma unroll
            for (int i = 0; i < TM; ++i) {
                int row = wr * WM + i * 32 + l31;
                int off = row * 32 + ((gk ^ (row & 3)) << 3);
                af[i] = *(const bf16x8*)&sAh[off];
                if constexpr (HAS_AL) alf[i] = *(const bf16x8*)&sAl[off];
            }
#pragma unroll
            for (int j = 0; j < TN; ++j) {
                int row = wc * WN + j * 32 + l31;
                int off = row * 32 + ((gk ^ (row & 3)) << 3);
                bfv[j] = *(const bf16x8*)&sBh[off];
                if constexpr (HAS_BL) blf[j] = *(const bf16x8*)&sBl[off];
            }
#pragma unroll
            for (int i = 0; i < TM; ++i)
#pragma unroll
                for (int j = 0; j < TN; ++j) {
                    acc[i][j] = __builtin_amdgcn_mfma_f32_32x32x16_bf16(af[i], bfv[j], acc[i][j], 0, 0, 0);
                    if constexpr (HAS_AL)
                        acc[i][j] = __builtin_amdgcn_mfma_f32_32x32x16_bf16(alf[i], bfv[j], acc[i][j], 0, 0, 0);
                    if constexpr (HAS_BL)
                        acc[i][j] = __builtin_amdgcn_mfma_f32_32x32x16_bf16(af[i], blf[j], acc[i][j], 0, 0, 0);
                }
        }
        __syncthreads();
    }
#pragma unroll
    for (int i = 0; i < TM; ++i)
#pragma unroll
        for (int j = 0; j < TN; ++j)
#pragma unroll
            for (int r = 0; r < 16; ++r) {
                int row = bm + wr * WM + i * 32 + (r & 3) + 8 * (r >> 2) + 4 * lh;
                int col = bn + wc * WN + j * 32 + l31;
                C[(size_t)row * ldc + col] = acc[i][j][r];
            }
}

// ---------------- causal depthwise conv (KSZ=4) + SiLU ----------------
__global__ __launch_bounds__(256) void conv_silu_k(const float* __restrict__ xin,
    const float* __restrict__ cw, const float* __restrict__ cb, float* __restrict__ xca)
{
    const int c = blockIdx.x * 256 + threadIdx.x;
    const int t = blockIdx.y;
    const int s = t & (SEQ_ - 1);
    const float w0 = cw[c*4+0], w1 = cw[c*4+1], w2 = cw[c*4+2], w3 = cw[c*4+3];
    const float* base = xin + (size_t)t * 2048 + c;
    float acc = cb[c];
    if (s >= 3) acc += base[-3*2048] * w0;
    if (s >= 2) acc += base[-2*2048] * w1;
    if (s >= 1) acc += base[-1*2048] * w2;
    acc += base[0] * w3;
    float sg = 1.f / (1.f + __expf(-acc));
    xca[(size_t)t * INNER_ + c] = acc * sg;
}

// ---------------- compose gate weights: M = blockdiag(Wq/Wk/Wv) folded into W_if ----------------
// m16[g][c], c<1024: q-part + k-part (applied to xca); c>=1024: v-part (applied to x_mlstm)
__global__ __launch_bounds__(256) void mcompose(const float* __restrict__ Wq,
    const float* __restrict__ Wk, const float* __restrict__ Wv,
    const float* __restrict__ Wif, bf16_t* __restrict__ m16)
{
    const int n = blockIdx.x;
    const int tid = threadIdx.x;
    const int g = tid >> 3, d0 = (tid & 7) << 3;
    float aq[8] = {}, av[8] = {};
    const float* wifq = Wif + (size_t)g * 3072 + n * 64;
    const float* wifk = wifq + 1024;
    const float* wifv = wifq + 2048;
    const float* wqb = Wq + n * 4096;
    const float* wkb = Wk + n * 4096;
    const float* wvb = Wv + n * 4096;
    for (int o = 0; o < 64; ++o) {
        float cq = wifq[o], ck = wifk[o], cv = wifv[o];
        const float* q4 = wqb + o * 64 + d0;
        const float* k4 = wkb + o * 64 + d0;
        const float* v4 = wvb + o * 64 + d0;
#pragma unroll
        for (int e = 0; e < 8; ++e) {
            aq[e] += cq * q4[e] + ck * k4[e];
            av[e] += cv * v4[e];
        }
    }
    bf16x8 oq, ov;
#pragma unroll
    for (int e = 0; e < 8; ++e) { oq[e] = (bf16_t)aq[e]; ov[e] = (bf16_t)av[e]; }
    *(bf16x8*)(m16 + (size_t)g * 2048 + n * 64 + d0) = oq;
    *(bf16x8*)(m16 + (size_t)g * 2048 + 1024 + n * 64 + d0) = ov;
}

// ---------------- gate pre-activation via composed M: ifp = xca@Mqk^T + xm@Mv^T ----------------
__global__ __launch_bounds__(512) void if_mfma2(const float* __restrict__ xca,
    const float* __restrict__ xin, const bf16_t* __restrict__ m16,
    float* __restrict__ ifp)
{
    __shared__ float red[8][32][33];
    const int t0g = blockIdx.x * 32;
    const int tid = threadIdx.x, w = tid >> 6, l = tid & 63, l31 = l & 31, lh = l >> 5;
    const int tok = t0g + l31;
    const bf16_t* mbase = m16 + (size_t)l31 * 2048 + 8 * lh;
    f32x16 acc;
#pragma unroll
    for (int r = 0; r < 16; ++r) acc[r] = 0.f;
    const int kw = w * 256;
#pragma unroll 4
    for (int it = 0; it < 16; ++it) {
        const int ksub = kw + it * 16 + 8 * lh;
        const float* ap = (ksub < 1024) ? (xca + (size_t)tok * 1024 + ksub)
                                        : (xin + (size_t)tok * 2048 + (ksub - 1024));
        float4 u0 = *(const float4*)ap, u1 = *(const float4*)(ap + 4);
        bf16x8 af;
        af[0] = (bf16_t)u0.x; af[1] = (bf16_t)u0.y; af[2] = (bf16_t)u0.z; af[3] = (bf16_t)u0.w;
        af[4] = (bf16_t)u1.x; af[5] = (bf16_t)u1.y; af[6] = (bf16_t)u1.z; af[7] = (bf16_t)u1.w;
        bf16x8 bf = *(const bf16x8*)(mbase + kw + it * 16);
        acc = __builtin_amdgcn_mfma_f32_32x32x16_bf16(af, bf, acc, 0, 0, 0);
    }
#pragma unroll
    for (int r = 0; r < 16; ++r) {
        int row = (r & 3) + 8 * (r >> 2) + 4 * lh;
        red[w][row][l31] = acc[r];
    }
    __syncthreads();
#pragma unroll
    for (int it = 0; it < 2; ++it) {
        int idx = tid + it * 512;
        int row = idx >> 5, colg = idx & 31;
        float s = 0.f;
#pragma unroll
        for (int ww = 0; ww < 8; ++ww) s += red[ww][row][colg];
        ifp[(size_t)(t0g + row) * 32 + colg] = s;
    }
}

// ---------------- per-(b,head) gate scan: outputs colfac, cmax, em ----------------
__global__ __launch_bounds__(256) void gate_scan(const float* __restrict__ ifp,
    const float* __restrict__ b_if, float* __restrict__ colfac,
    float* __restrict__ cmaxv, float* __restrict__ emv)
{
    __shared__ float tots[256];
    __shared__ float cmE[32];
    const int bn = blockIdx.x;
    const int b = bn >> 4, n = bn & 15;
    const int tid = threadIdx.x;
    const float bi = b_if[n], bf = b_if[16 + n];
    const int s0 = tid * 8;
    float iv[8], lf[8];
#pragma unroll
    for (int j = 0; j < 8; ++j) {
        size_t row = ((size_t)b * SEQ_ + s0 + j) * 32;
        float ip = ifp[row + n] + bi;        ip = CAPV * tanhf(ip * (1.f / CAPV));
        float fp = ifp[row + 16 + n] + bf;   fp = CAPV * tanhf(fp * (1.f / CAPV));
        float ls = fminf(fp, 0.f) - log1pf(expf(-fabsf(fp)));
        iv[j] = ip; lf[j] = ls;
    }
#pragma unroll
    for (int j = 1; j < 8; ++j) lf[j] += lf[j-1];
    tots[tid] = lf[7];
    __syncthreads();
    for (int off = 1; off < 256; off <<= 1) {
        float o = (tid >= off) ? tots[tid - off] : 0.f;
        __syncthreads();
        tots[tid] += o;
        __syncthreads();
    }
    const float exs = (tid > 0) ? tots[tid - 1] : 0.f;
    float Fc[8], a[8], am[8];
#pragma unroll
    for (int j = 0; j < 8; ++j) { Fc[j] = exs + lf[j]; a[j] = iv[j] - Fc[j]; }
    am[0] = a[0];
#pragma unroll
    for (int j = 1; j < 8; ++j) am[j] = fmaxf(am[j-1], a[j]);
    __syncthreads();
    tots[tid] = am[7];
    __syncthreads();
    for (int off = 1; off < 256; off <<= 1) {
        float o = (tid >= off) ? tots[tid - off] : -INFINITY;
        __syncthreads();
        tots[tid] = fmaxf(tots[tid], o);
        __syncthreads();
    }
    const float exm = (tid > 0) ? tots[tid - 1] : -INFINITY;
    if ((tid & 7) == 7) cmE[tid >> 3] = fmaxf(exm, am[7]);
    __syncthreads();
    const float ce = cmE[tid >> 3];
    const size_t base = (size_t)bn * SEQ_ + s0;
#pragma unroll
    for (int j = 0; j < 8; ++j) {
        float cm = fmaxf(exm, am[j]);
        colfac[base + j] = __expf(a[j] - ce);
        cmaxv[base + j]  = cm;
        emv[base + j]    = expf(-(Fc[j] + cm));
    }
}

// ---------------- per-head q/k/v projections via MFMA -> bf16 buffers ----------------
// (vb16 removed: gate path no longer consumes row-major v)
__global__ __launch_bounds__(256) void qkv_mfma(const float* __restrict__ xca,
    const float* __restrict__ xin, const float* __restrict__ Wq,
    const float* __restrict__ Wk, const float* __restrict__ Wv,
    bf16_t* __restrict__ qb16, bf16_t* __restrict__ kb16, bf16_t* __restrict__ vbt16)
{
    __shared__ __align__(16) bf16_t Xs[128 * 64];
    __shared__ __align__(16) bf16_t Ws[64 * 64];
    const int mt = blockIdx.x, n = blockIdx.y, which = blockIdx.z;
    const int t0 = mt * 128, b = t0 >> 11, s0 = t0 & (SEQ_ - 1);
    const float* X = (which == 2) ? xin : xca;
    const size_t xpitch = (which == 2) ? 2048 : 1024;
    const float* W = ((which == 0) ? Wq : (which == 1) ? Wk : Wv) + n * 4096;
    const int tid = threadIdx.x, w = tid >> 6, l = tid & 63, l31 = l & 31, lh = l >> 5;
    const size_t gbn = (size_t)(b * NHEAD + n) * SEQ_;

#pragma unroll
    for (int it = 0; it < 4; ++it) {
        int gi = tid + it * 256; int row = gi >> 3, g = gi & 7;
        const float* src = X + (size_t)(t0 + row) * xpitch + n * 64 + g * 8;
        float4 u0 = *(const float4*)src, u1 = *(const float4*)(src + 4);
        float va[8] = {u0.x, u0.y, u0.z, u0.w, u1.x, u1.y, u1.z, u1.w};
        bf16x8 h;
#pragma unroll
        for (int e = 0; e < 8; ++e) h[e] = (bf16_t)va[e];
        *(bf16x8*)&Xs[row * 64 + ((g ^ (row & 7)) << 3)] = h;
    }
#pragma unroll
    for (int it = 0; it < 2; ++it) {
        int gi = tid + it * 256; int row = gi >> 3, g = gi & 7;
        const float* src = W + row * 64 + g * 8;
        float4 u0 = *(const float4*)src, u1 = *(const float4*)(src + 4);
        float va[8] = {u0.x, u0.y, u0.z, u0.w, u1.x, u1.y, u1.z, u1.w};
        bf16x8 h;
#pragma unroll
        for (int e = 0; e < 8; ++e) h[e] = (bf16_t)va[e];
        *(bf16x8*)&Ws[row * 64 + ((g ^ (row & 7)) << 3)] = h;
    }
    __syncthreads();

    if (which < 2) {
        const int wr = w >> 1, wc = w & 1;
        f32x16 acc[2];
#pragma unroll
        for (int i = 0; i < 2; ++i)
#pragma unroll
            for (int r = 0; r < 16; ++r) acc[i][r] = 0.f;
#pragma unroll
        for (int ks = 0; ks < 4; ++ks) {
            const int gk = 2 * ks + lh;
            const int wrow = wc * 32 + l31;
            bf16x8 bfrag = *(const bf16x8*)&Ws[wrow * 64 + ((gk ^ (wrow & 7)) << 3)];
#pragma unroll
            for (int i = 0; i < 2; ++i) {
                int row = wr * 64 + i * 32 + l31;
                bf16x8 afrag = *(const bf16x8*)&Xs[row * 64 + ((gk ^ (row & 7)) << 3)];
                acc[i] = __builtin_amdgcn_mfma_f32_32x32x16_bf16(afrag, bfrag, acc[i], 0, 0, 0);
            }
        }
        bf16_t* dst = which ? kb16 : qb16;
#pragma unroll
        for (int i = 0; i < 2; ++i)
#pragma unroll
            for (int r = 0; r < 16; ++r) {
                int srow = wr * 64 + i * 32 + (r & 3) + 8 * (r >> 2) + 4 * lh;
                dst[(gbn + s0 + srow) * 64 + wc * 32 + l31] = (bf16_t)acc[i][r];
            }
    } else {
        const int dh = w >> 1, th = w & 1;
        f32x16 acc[2];
#pragma unroll
        for (int j = 0; j < 2; ++j)
#pragma unroll
            for (int r = 0; r < 16; ++r) acc[j][r] = 0.f;
#pragma unroll
        for (int ks = 0; ks < 4; ++ks) {
            const int gk = 2 * ks + lh;
            const int wrow = dh * 32 + l31;
            bf16x8 afrag = *(const bf16x8*)&Ws[wrow * 64 + ((gk ^ (wrow & 7)) << 3)];
#pragma unroll
            for (int j = 0; j < 2; ++j) {
                int xrow = th * 64 + j * 32 + l31;
                bf16x8 bfrag = *(const bf16x8*)&Xs[xrow * 64 + ((gk ^ (xrow & 7)) << 3)];
                acc[j] = __builtin_amdgcn_mfma_f32_32x32x16_bf16(afrag, bfrag, acc[j], 0, 0, 0);
            }
        }
        const size_t vtb = (size_t)(b * NHEAD + n) * 64;
#pragma unroll
        for (int j = 0; j < 2; ++j)
#pragma unroll
            for (int r = 0; r < 16; ++r) {
                int drow = dh * 32 + (r & 3) + 8 * (r >> 2) + 4 * lh;
                int tcol = th * 64 + j * 32 + l31;
                vbt16[(vtb + drow) * SEQ_ + s0 + tcol] = (bf16_t)acc[j][r];
            }
    }
}

// ---------------- fold 0.125*colfac into k (in-place) ----------------
__global__ __launch_bounds__(256) void kscale(bf16_t* __restrict__ kb16,
    const float* __restrict__ colfac)
{
    const int i = blockIdx.x * 256 + threadIdx.x;
    const int row = i >> 3, c = (i & 7) << 3;
    const float cf = 0.125f * colfac[row];
    bf16x8 v = *(const bf16x8*)(kb16 + (size_t)row * 64 + c);
#pragma unroll
    for (int e = 0; e < 8; ++e) v[e] = (bf16_t)((float)v[e] * cf);
    *(bf16x8*)(kb16 + (size_t)row * 64 + c) = v;
}

__device__ inline unsigned pack2(float a, float b) {
    union { bf16_t h; unsigned short u; } ua, ub;
    ua.h = (bf16_t)a; ub.h = (bf16_t)b;
    return (unsigned)ua.u | ((unsigned)ub.u << 16);
}

// ---------------- causal mLSTM: swapped-QK, register P, rank-1 decay ----------------
// VERIFIED round-10 body; changes: (1) csum via ones-B MFMA into cs[] (removes the
// serial 32-add VALU chain + csum shuffles + inv_lds + one barrier), (2) em via LDS,
// (3) launch_bounds (256,4) for one more block/CU.
__global__ __launch_bounds__(256, 4) void mlstm_k3b(
    const bf16_t* __restrict__ qb16, const bf16_t* __restrict__ khat,
    const bf16_t* __restrict__ vbt16,
    const float* __restrict__ cmaxv, const float* __restrict__ emv,
    const float* __restrict__ xca, const float* __restrict__ xin,
    const float* __restrict__ norm_w, const float* __restrict__ skipv,
    float* __restrict__ houtp)
{
    __shared__ __align__(16) bf16_t ks[2][64*64];
    __shared__ __align__(16) bf16_t vts[2][64*64];
    __shared__ float cmB_sh[32];
    __shared__ float em_sh[64];
    __shared__ float red_lds[2][2][2][16];   // [sh][dh][lh][reg]

    // XCD-pinned bijective decode: bid in [0,1024) -> (head in [0,32), st in [0,32))
    const int bid = blockIdx.x;
    const int r8 = bid & 7, rem = bid >> 3;
    const int jj = rem & 31, qq = rem >> 5;
    const int bnh = r8 + 8 * qq;
    const int b = bnh >> 4, n = bnh & 15;
    const int st = 31 - jj;

    const int tid = threadIdx.x, w = tid >> 6, l = tid & 63;
    const int l31 = l & 31, lh = l >> 5;
    const int sh = w >> 1, dh = w & 1;
    const size_t gb = (size_t)(b * NHEAD + n) * SEQ_;
    const int s_lane = 32 * sh + l31;
    const int d_lane = 32 * dh + l31;

    const float cmq = cmaxv[gb + (size_t)st * 64 + s_lane];
    const int col = n * 64 + d_lane;
    const float gn = 1.f + norm_w[col];
    const float sk = skipv[col];
    if (tid < 32) cmB_sh[tid] = cmaxv[gb + (size_t)tid * 64 + 63];
    if (tid < 64) em_sh[tid] = emv[gb + (size_t)st * 64 + tid];

    bf16x8 qf[4];
    {
        const bf16_t* qp = qb16 + (gb + (size_t)st * 64 + s_lane) * 64 + 8 * lh;
#pragma unroll
        for (int kc = 0; kc < 4; ++kc) qf[kc] = *(const bf16x8*)(qp + 16 * kc);
    }
    bf16x8 onesf;
#pragma unroll
    for (int e = 0; e < 8; ++e) onesf[e] = (bf16_t)1.0f;

    f32x16 hac, cs;
#pragma unroll
    for (int i = 0; i < 16; ++i) { hac[i] = 0.f; cs[i] = 0.f; }

    const bf16_t* kbase = khat + gb * 64;
    const bf16_t* vbase = vbt16 + (size_t)(b * NHEAD + n) * 64 * SEQ_;

#define STAGE(buf, ttv) { \
    const bf16_t* kgp = kbase + (size_t)(ttv) * 64 * 64; \
    const bf16_t* vgp = vbase + (size_t)(ttv) * 64; \
    _Pragma("unroll") \
    for (int it_ = 0; it_ < 2; ++it_) { \
        int id_ = tid + it_ * 256; \
        int r_ = id_ >> 3, c_ = (id_ & 7) << 3; \
        int sw_ = c_ ^ ((r_ & 7) << 3); \
        *(bf16x8*)&ks[buf][r_ * 64 + sw_] = *(const bf16x8*)(kgp + r_ * 64 + c_); \
        *(bf16x8*)&vts[buf][r_ * 64 + sw_] = *(const bf16x8*)(vgp + (size_t)r_ * SEQ_ + c_); \
    } }

    STAGE(0, 0)
    int cur = 0;
    for (int tt = 0; tt <= st; ++tt) {
        __syncthreads();
        if (tt < st) STAGE(cur ^ 1, tt + 1)
        const float rf = __expf(cmB_sh[tt] - cmq);
        const bool diag = (tt == st);
#pragma unroll
        for (int tq = 0; tq < 2; ++tq) {
            if (diag && sh == 0 && tq == 1) continue;   // fully-masked quadrant (wave-uniform)
            f32x16 p;
#pragma unroll
            for (int i = 0; i < 16; ++i) p[i] = 0.f;
            const int krow = 32 * tq + l31;
            const int swk = (krow & 7) << 3;
#pragma unroll
            for (int kc = 0; kc < 4; ++kc) {
                bf16x8 kf = *(const bf16x8*)&ks[cur][krow * 64 + ((8 * lh + 16 * kc) ^ swk)];
                p = __builtin_amdgcn_mfma_f32_32x32x16_bf16(kf, qf[kc], p, 0, 0, 0);
            }
#pragma unroll
            for (int reg = 0; reg < 16; ++reg) {
                const int t_loc = (reg & 3) + 8 * (reg >> 2) + 4 * lh + 32 * tq;
                float pw = p[reg] * rf;
                if (diag && t_loc > s_lane) pw = 0.f;
                p[reg] = pw;
            }
            unsigned W0 = pack2(p[0],  p[1]),  W1 = pack2(p[2],  p[3]);
            unsigned W2 = pack2(p[4],  p[5]),  W3 = pack2(p[6],  p[7]);
            unsigned W4 = pack2(p[8],  p[9]),  W5 = pack2(p[10], p[11]);
            unsigned W6 = pack2(p[12], p[13]), W7 = pack2(p[14], p[15]);
            unsigned r1 = __shfl_xor(lh ? W0 : W2, 32, 64);
            unsigned r2 = __shfl_xor(lh ? W1 : W3, 32, 64);
            unsigned r3 = __shfl_xor(lh ? W4 : W6, 32, 64);
            unsigned r4 = __shfl_xor(lh ? W5 : W7, 32, 64);
            u32x4 pa0 = lh ? (u32x4){r1, r2, W2, W3} : (u32x4){W0, W1, r1, r2};
            u32x4 pa1 = lh ? (u32x4){r3, r4, W6, W7} : (u32x4){W4, W5, r3, r4};
            const int swv = (d_lane & 7) << 3;
#pragma unroll
            for (int kcl = 0; kcl < 2; ++kcl) {
                const int kcg = 2 * tq + kcl;
                bf16x8 vf = *(const bf16x8*)&vts[cur][d_lane * 64 + ((8 * lh + 16 * kcg) ^ swv)];
                bf16x8 paf = __builtin_bit_cast(bf16x8, kcl ? pa1 : pa0);
                hac = __builtin_amdgcn_mfma_f32_32x32x16_bf16(paf, vf, hac, 0, 0, 0);
                cs  = __builtin_amdgcn_mfma_f32_32x32x16_bf16(paf, onesf, cs, 0, 0, 0);
            }
        }
        cur ^= 1;
    }
#undef STAGE

    // ---- epilogue: cs[reg] = row-sum for s = 32*sh + s_loc(reg) (identical on all lanes) ----
    float sq[16];
#pragma unroll
    for (int reg = 0; reg < 16; ++reg) {
        const int s_loc = (reg & 3) + 8 * (reg >> 2) + 4 * lh;
        const float den = fmaxf(fabsf(cs[reg]), em_sh[32 * sh + s_loc]) + EPS_;
        float h = hac[reg] / den;
        hac[reg] = h;
        float s2 = h * h;
        s2 += __shfl_xor(s2, 1);  s2 += __shfl_xor(s2, 2);
        s2 += __shfl_xor(s2, 4);  s2 += __shfl_xor(s2, 8);
        s2 += __shfl_xor(s2, 16);
        sq[reg] = s2;
    }
    if (l31 == 0) {
#pragma unroll
        for (int reg = 0; reg < 16; ++reg) red_lds[sh][dh][lh][reg] = sq[reg];
    }
    __syncthreads();
#pragma unroll
    for (int reg = 0; reg < 16; ++reg) {
        const int s_loc = (reg & 3) + 8 * (reg >> 2) + 4 * lh;
        const float ssq = red_lds[sh][0][lh][reg] + red_lds[sh][1][lh][reg];
        const float rr = rsqrtf(ssq * (1.f / 64.f) + NEPS);
        const size_t tok = (size_t)b * SEQ_ + (size_t)st * 64 + 32 * sh + s_loc;
        float ht = hac[reg] * rr * gn + sk * xca[tok * INNER_ + col];
        float zz = xin[tok * 2048 + 1024 + col];
        float sil = zz / (1.f + __expf(-zz));
        houtp[tok * 2048 + col] = ht * sil;
    }
}

extern "C" void kernel_launch(void* const* d_in, const int* in_sizes, int n_in,
                              void* d_out, int out_size, void* d_ws, size_t ws_size,
                              hipStream_t stream)
{
    const float* x      = (const float*)d_in[0];
    const float* W_up   = (const float*)d_in[1];
    const float* W_q    = (const float*)d_in[2];
    const float* W_k    = (const float*)d_in[3];
    const float* W_v    = (const float*)d_in[4];
    const float* conv_w = (const float*)d_in[5];
    const float* conv_b = (const float*)d_in[6];
    const float* W_if   = (const float*)d_in[7];
    const float* b_if   = (const float*)d_in[8];
    const float* norm_w = (const float*)d_in[9];
    const float* skip   = (const float*)d_in[10];
    const float* W_down = (const float*)d_in[11];
    float* out = (float*)d_out;

    float* xin    = (float*)d_ws;                          // TOK x 2048 (x_mlstm|z, later h|z)
    float* xca    = xin  + (size_t)TOK * 2048;             // TOK x 1024
    float* ifp    = xca  + (size_t)TOK * INNER_;           // TOK x 32
    float* colfac = ifp  + (size_t)TOK * 32;               // B*NH*S
    float* cmaxv  = colfac + (size_t)BATCH * NHEAD * SEQ_;
    float* emv    = cmaxv  + (size_t)BATCH * NHEAD * SEQ_;
    bf16_t* qb16  = (bf16_t*)(emv + (size_t)BATCH * NHEAD * SEQ_);
    bf16_t* kb16  = qb16 + (size_t)TOK * INNER_;
    bf16_t* vbt16 = kb16 + (size_t)TOK * INNER_;
    bf16_t* m16   = vbt16 + (size_t)TOK * INNER_;          // 32 x 2048

    gemm_split<128,128,64,64,3><<<dim3(2048/128, TOK/128), 256, 0, stream>>>(
        x, W_up, xin, DIM_, DIM_, DIM_, 2048);
    conv_silu_k<<<dim3(INNER_/256, TOK), 256, 0, stream>>>(xin, conv_w, conv_b, xca);
    mcompose<<<dim3(NHEAD), 256, 0, stream>>>(W_q, W_k, W_v, W_if, m16);
    if_mfma2<<<dim3(TOK/32), 512, 0, stream>>>(xca, xin, m16, ifp);
    gate_scan<<<dim3(BATCH*NHEAD), 256, 0, stream>>>(ifp, b_if, colfac, cmaxv, emv);
    qkv_mfma<<<dim3(TOK/128, NHEAD, 3), 256, 0, stream>>>(xca, xin, W_q, W_k, W_v,
        qb16, kb16, vbt16);
    kscale<<<dim3(TOK*INNER_/8/256), 256, 0, stream>>>(kb16, colfac);
    mlstm_k3b<<<dim3(1024), 256, 0, stream>>>(qb16, kb16, vbt16,
        cmaxv, emv, xca, xin, norm_w, skip, xin /*h overlays x_mlstm half*/);
    // down-projection: MODE=2 (drop AhBl; |W_down| tiny -> ~2.5e-4 extra error)
    gemm_split<128,64,32,64,2><<<dim3(DIM_/64, TOK/128), 256, 0, stream>>>(
        xin, W_down, out, INNER_, 2048, INNER_, DIM_);
}